// Round 11
// baseline (319.012 us; speedup 1.0000x reference)
//
#include <hip/hip_runtime.h>

// DTTreeGRU: L=1024, B=64, D=256, H=256, K=4 (tree arity)
// Heap tree: internal nodes 0..255, leaves 256..1023 (children 4n+1..4n+4).
// Internal levels (bottom-up): starts {0,1,5,21,85}, counts {1,4,16,64,171}.
// Leaves: lh=rh=0 -> h = sigmoid(x@Wz^T+bz) * tanh(x@Wc^T+bc): one GEMM over
// interleaved Wl (512 x 256; 16-col z/c groups so z,c pair within one wave).
//
// r11: LDS-BW diagnosis (r10): 128^2 tile w/ both operands in LDS moves
// 112KB/K-step through the 85B/cyc LDS port vs 621cyc of MFMA -> 2.1x
// LDS-bound. Fix: A-fragments DIRECT from global/L2 (reg-prefetched 1
// K-step ahead), only B staged in LDS (Bs dbuf 36KB). Pipes now balanced
// (LDS ~850 / MFMA ~620 / L2-A ~585 cyc per block-K-step).
// Also: cell/leaf epilogues write fp32 out directly; k_write_out dropped.

#define L_TOT 1024

typedef __attribute__((ext_vector_type(8))) short short8;
typedef __attribute__((ext_vector_type(4))) short short4v;
typedef __attribute__((ext_vector_type(4))) float f32x4;

static __device__ __forceinline__ float bf2f(unsigned short u) {
  unsigned int x = ((unsigned int)u) << 16;
  return __builtin_bit_cast(float, x);
}
static __device__ __forceinline__ unsigned short f2bf(float f) {
  unsigned int u = __builtin_bit_cast(unsigned int, f);
  u += 0x7fffu + ((u >> 16) & 1u);
  return (unsigned short)(u >> 16);
}
static __device__ __forceinline__ float sigmf(float x) { return 1.0f / (1.0f + __expf(-x)); }
static __device__ __forceinline__ float tanhf_(float x) { return 2.0f / (1.0f + __expf(-2.0f * x)) - 1.0f; }

// lgkm-only barrier: LDS ops visible, global loads stay in flight
static __device__ __forceinline__ void bar_lgkm() {
  asm volatile("s_waitcnt lgkmcnt(0)" ::: "memory");
  __builtin_amdgcn_s_barrier();
  __builtin_amdgcn_sched_barrier(0);
}

// bijective XCD swizzle (m204): contiguous logical range per XCD
static __device__ __forceinline__ int swz_t(int orig, int nwg) {
  int q = nwg >> 3, r = nwg & 7, x = orig & 7, s = orig >> 3;
  return (x < r ? x * (q + 1) : r * (q + 1) + (x - r) * q) + s;
}

// ---- prologue: convert INTERNAL x rows -> bf16, build weights, zero pad ----
__global__ __launch_bounds__(256) void k_pre(
    const float* __restrict__ in,
    const float* __restrict__ Wgih, const float* __restrict__ Wglh, const float* __restrict__ Wgrh,
    const float* __restrict__ Wcih, const float* __restrict__ Wclh, const float* __restrict__ Wcrh,
    unsigned short* __restrict__ xb, unsigned short* __restrict__ Wg,
    unsigned short* __restrict__ Wc, unsigned short* __restrict__ Wl,
    unsigned short* __restrict__ hb) {
  int t = blockIdx.x * 256 + threadIdx.x;
  if (t < 524288) {
    const float* s = in + (size_t)t * 8;
    short8 v;
#pragma unroll
    for (int j = 0; j < 8; ++j) v[j] = (short)f2bf(s[j]);
    *(short8*)(xb + (size_t)t * 8) = v;
  }
  const int NG = 1280 * 768;
  const int NC = 256 * 768;
  const int NL = 512 * 256;
  if (t < NG) {
    int g = t / 768, k = t % 768;
    float v = (k < 256) ? Wgih[g * 256 + k] : ((k < 512) ? Wglh[g * 256 + k - 256] : Wgrh[g * 256 + k - 512]);
    Wg[t] = f2bf(v);
  } else if (t < NG + NC) {
    int t2 = t - NG;
    int g = t2 / 768, k = t2 % 768;
    float v = (k < 256) ? Wcih[g * 256 + k] : ((k < 512) ? Wclh[g * 256 + k - 256] : Wcrh[g * 256 + k - 512]);
    Wc[t2] = f2bf(v);
  } else if (t < NG + NC + NL) {
    int t2 = t - NG - NC;
    int n = t2 >> 8, k = t2 & 255;
    int g = n >> 4;
    int hc = (g >> 1) * 16 + (n & 15);
    float v = (g & 1) ? Wcih[hc * 256 + k] : Wgih[(1024 + hc) * 256 + k];
    Wl[t2] = f2bf(v);
  }
  if (t < 16384) hb[(size_t)1024 * 16384 + t] = 0;
}

// ---- per-level: lh = h[c0]+h[c1], rh = h[c2]+h[c3]; 8 elems/thread ----
__global__ __launch_bounds__(256) void k_prep(const unsigned short* __restrict__ hb,
                                              unsigned short* __restrict__ lh,
                                              unsigned short* __restrict__ rh,
                                              int rows, int row_off, int lvl_start) {
  int t = blockIdx.x * 256 + threadIdx.x;
  if (t >= rows * 32) return;
  int r = t >> 5, k8 = (t & 31) << 3;
  int gr = row_off + r;
  int node = lvl_start + (gr >> 6);
  int b = gr & 63;
  int cb = 4 * node + 1;
  int c0 = cb, c1 = cb + 1, c2 = cb + 2, c3 = cb + 3;
  c0 = (c0 < L_TOT) ? c0 : L_TOT;
  c1 = (c1 < L_TOT) ? c1 : L_TOT;
  c2 = (c2 < L_TOT) ? c2 : L_TOT;
  c3 = (c3 < L_TOT) ? c3 : L_TOT;
  const short8 v0 = *(const short8*)(hb + (size_t)c0 * 16384 + b * 256 + k8);
  const short8 v1 = *(const short8*)(hb + (size_t)c1 * 16384 + b * 256 + k8);
  const short8 v2 = *(const short8*)(hb + (size_t)c2 * 16384 + b * 256 + k8);
  const short8 v3 = *(const short8*)(hb + (size_t)c3 * 16384 + b * 256 + k8);
  short8 ol, orr;
#pragma unroll
  for (int j = 0; j < 8; ++j) {
    ol[j] = (short)f2bf(bf2f((unsigned short)v0[j]) + bf2f((unsigned short)v1[j]));
    orr[j] = (short)f2bf(bf2f((unsigned short)v2[j]) + bf2f((unsigned short)v3[j]));
  }
  *(short8*)(lh + (size_t)r * 256 + k8) = ol;
  *(short8*)(rh + (size_t)r * 256 + k8) = orr;
}

// ---- A-direct MFMA GEMM: 128x128 tile, 8 waves, B-only LDS (dbuf, LR=72) ----
// A-fragments read straight from global (L2-hot via XCD swizzle), register-
// prefetched one K-step ahead. Swapped-operand MFMA (C^T lane map).
// EPI 0: gates (N=1280, K=768): sigmoid + vector scatter a2l/a2r/p1/p2/zb
// EPI 1: cell  (N=256,  K=768): tanh + hidden -> hb (bf16) + out (fp32)
template <int EPI>
static __device__ __forceinline__ void gemm_adirect(
    const unsigned short* __restrict__ Aseg0,
    const unsigned short* __restrict__ Aseg1,
    const unsigned short* __restrict__ Aseg2,
    const unsigned short* __restrict__ Wt, const float* __restrict__ bias,
    int rows, int row_off, int lvl_start, int NT, int nwg,
    const unsigned short* __restrict__ lh, const unsigned short* __restrict__ rh,
    unsigned short* __restrict__ a2l, unsigned short* __restrict__ a2r,
    unsigned short* __restrict__ p1, unsigned short* __restrict__ p2,
    unsigned short* __restrict__ zb, unsigned short* __restrict__ hb,
    float* __restrict__ out) {
  constexpr int NKT = 12;   // K-steps of 64 (K=768)
  constexpr int LR = 72;    // padded LDS row; 144 B = 9*16B
  int t = swz_t(blockIdx.x, nwg);
  int tm = t / NT, tn = t % NT;
  const int tid = threadIdx.x, lane = tid & 63, wave = tid >> 6;
  const int wr = wave >> 1, wcl = wave & 1;  // 4x2 wave grid; wave owns 32x64

  __shared__ unsigned short Bs[2][128 * LR];   // 36864 B total

  f32x4 acc[2][4];
#pragma unroll
  for (int i = 0; i < 2; ++i)
#pragma unroll
    for (int j = 0; j < 4; ++j) {
      f32x4 zv = {0.f, 0.f, 0.f, 0.f};
      acc[i][j] = zv;
    }

  const unsigned short* segs[3] = {Aseg0, Aseg1, Aseg2};
  const int srow = tid >> 3;
  const int scol = (tid & 7) * 8;

  short8 rvb[3][2];        // B staging, PF3
  short8 afr[2][2][2];     // A-frag prefetch: [set][mf][kk]

  const size_t arow_base = (size_t)(tm * 128 + wr * 32 + (lane & 15)) * 256;
  const int acol = (lane >> 4) * 8;

  auto LOADA = [&](int kt, int s) {
    const unsigned short* segp = segs[kt >> 2];
    int ko = (kt & 3) * 64 + acol;
#pragma unroll
    for (int mf = 0; mf < 2; ++mf)
#pragma unroll
      for (int kk = 0; kk < 2; ++kk)
        afr[s][mf][kk] = *(const short8*)(segp + arow_base + (size_t)mf * 16 * 256 + ko + kk * 32);
  };
  auto LOADB = [&](int kt, int s) {
#pragma unroll
    for (int i = 0; i < 2; ++i)
      rvb[s][i] = *(const short8*)(Wt + (size_t)(tn * 128 + srow + i * 64) * 768 + kt * 64 + scol);
  };
  auto WRITEB = [&](int s, int buf) {
#pragma unroll
    for (int i = 0; i < 2; ++i)
      *(short8*)(&Bs[buf][(srow + i * 64) * LR + scol]) = rvb[s][i];
  };

  // prologue: A-frags for tile 0; 3 B tiles in flight; B tile 0 into buf0
  LOADA(0, 0);
  LOADB(0, 0);
  LOADB(1, 1);
  LOADB(2, 2);
  WRITEB(0, 0);
  bar_lgkm();

#pragma unroll
  for (int kt = 0; kt < NKT; ++kt) {
    const int cur = kt & 1;
    if (kt + 1 < NKT) LOADA(kt + 1, cur ^ 1);         // A prefetch (L2)
    if (kt + 1 < NKT) WRITEB((kt + 1) % 3, cur ^ 1);  // counted vmcnt on B kt+1
    if (kt + 3 < NKT) LOADB(kt + 3, kt % 3);          // refill freed B set
#pragma unroll
    for (int kk = 0; kk < 2; ++kk) {
      short8 bf[4];
#pragma unroll
      for (int nf = 0; nf < 4; ++nf)
        bf[nf] = *(const short8*)(&Bs[cur][(wcl * 64 + nf * 16 + (lane & 15)) * LR + kk * 32 + (lane >> 4) * 8]);
      // swapped operands: acc = W-frag x A-frag = C^T fragment
#pragma unroll
      for (int mf = 0; mf < 2; ++mf)
#pragma unroll
        for (int nf = 0; nf < 4; ++nf)
          acc[mf][nf] = __builtin_amdgcn_mfma_f32_16x16x32_bf16(bf[nf], afr[cur][mf][kk], acc[mf][nf], 0, 0, 0);
    }
    if (kt + 1 < NKT) bar_lgkm();
  }

  // ---- epilogue: C^T lane map: m-row = ..+(lane&15), n-col quad = ..+(lane>>4)*4+j ----
#pragma unroll
  for (int nf = 0; nf < 4; ++nf) {
    int colq = tn * 128 + wcl * 64 + nf * 16 + (lane >> 4) * 4;
    f32x4 bsv = *(const f32x4*)(bias + colq);
    if (EPI == 0) {
      int ck = colq >> 8;        // uniform per block
      int gcq = colq & 255;
#pragma unroll
      for (int mf = 0; mf < 2; ++mf) {
        int r = tm * 128 + wr * 32 + mf * 16 + (lane & 15);
        if (r < rows) {
          size_t idx = (size_t)r * 256 + gcq;
          f32x4 s;
#pragma unroll
          for (int j = 0; j < 4; ++j) s[j] = sigmf(acc[mf][nf][j] + bsv[j]);
          short4v res;
          if (ck == 4) {
#pragma unroll
            for (int j = 0; j < 4; ++j) res[j] = (short)f2bf(s[j]);
            *(short4v*)(zb + idx) = res;
          } else {
            const unsigned short* src = (ck == 0 || ck == 2) ? lh : rh;
            short4v hv = *(const short4v*)(src + idx);
#pragma unroll
            for (int j = 0; j < 4; ++j) res[j] = (short)f2bf(s[j] * bf2f((unsigned short)hv[j]));
            if (ck == 0)      *(short4v*)(a2l + idx) = res;
            else if (ck == 1) *(short4v*)(a2r + idx) = res;
            else if (ck == 2) *(short4v*)(p1 + idx) = res;
            else              *(short4v*)(p2 + idx) = res;
          }
        }
      }
    } else {
#pragma unroll
      for (int mf = 0; mf < 2; ++mf) {
        int r = tm * 128 + wr * 32 + mf * 16 + (lane & 15);
        if (r < rows) {
          size_t idx = (size_t)r * 256 + colq;
          short4v p1v = *(const short4v*)(p1 + idx);
          short4v p2v = *(const short4v*)(p2 + idx);
          short4v zbv = *(const short4v*)(zb + idx);
          int gr = row_off + r;
          int node = lvl_start + (gr >> 6);
          int b = gr & 63;
          short4v hv;
          float4 ov;
          float hidv[4];
#pragma unroll
          for (int j = 0; j < 4; ++j) {
            float cell = tanhf_(acc[mf][nf][j] + bsv[j]);
            float hid = bf2f((unsigned short)p1v[j]) + bf2f((unsigned short)p2v[j]) +
                        bf2f((unsigned short)zbv[j]) * cell;
            hv[j] = (short)f2bf(hid);
            hidv[j] = hid;
          }
          ov.x = hidv[0]; ov.y = hidv[1]; ov.z = hidv[2]; ov.w = hidv[3];
          *(short4v*)(hb + (size_t)node * 16384 + b * 256 + colq) = hv;
          int jj = node ? (node - 1) : 1023;
          *(float4*)(out + (size_t)b * 262144 + (size_t)jj * 256 + colq) = ov;
          if (node == 0)
            *(float4*)(out + 16777216 + (size_t)b * 256 + colq) = ov;
        }
      }
    }
  }
}

__global__ __launch_bounds__(512, 4) void k_gates(
    const unsigned short* __restrict__ A0, const unsigned short* __restrict__ A1,
    const unsigned short* __restrict__ A2, const unsigned short* __restrict__ Wt,
    const float* __restrict__ bias, int rows, int row_off, int lvl_start, int nwg,
    const unsigned short* __restrict__ lh, const unsigned short* __restrict__ rh,
    unsigned short* __restrict__ a2l, unsigned short* __restrict__ a2r,
    unsigned short* __restrict__ p1, unsigned short* __restrict__ p2,
    unsigned short* __restrict__ zb) {
  gemm_adirect<0>(A0, A1, A2, Wt, bias, rows, row_off, lvl_start, 10, nwg,
                  lh, rh, a2l, a2r, p1, p2, zb, nullptr, nullptr);
}

__global__ __launch_bounds__(512, 4) void k_cell(
    const unsigned short* __restrict__ A0, const unsigned short* __restrict__ A1,
    const unsigned short* __restrict__ A2, const unsigned short* __restrict__ Wt,
    const float* __restrict__ bias, int rows, int row_off, int lvl_start, int nwg,
    const unsigned short* __restrict__ p1, const unsigned short* __restrict__ p2,
    const unsigned short* __restrict__ zb, unsigned short* __restrict__ hb,
    float* __restrict__ out) {
  gemm_adirect<1>(A0, A1, A2, Wt, bias, rows, row_off, lvl_start, 2, nwg,
                  nullptr, nullptr, nullptr, nullptr, (unsigned short*)p1,
                  (unsigned short*)p2, (unsigned short*)zb, hb, out);
}

// ---- leaf kernel: r10 body (As+Bs LDS, PF3, fp32-direct A) + fp32 out ----
__global__ __launch_bounds__(512, 4) void k_leaf(
    const float* __restrict__ Af, const unsigned short* __restrict__ Wt,
    const float* __restrict__ bias, const float* __restrict__ bias2, int nwg,
    unsigned short* __restrict__ hb, float* __restrict__ out) {
  constexpr int NKT = 4;    // K-steps of 64 (K=256)
  constexpr int LR = 72;
  int t = swz_t(blockIdx.x, nwg);
  int tm = t / 4, tn = t % 4;
  const int tid = threadIdx.x, lane = tid & 63, wave = tid >> 6;
  const int wr = wave >> 1, wcl = wave & 1;

  __shared__ unsigned short As[2][128 * LR];
  __shared__ unsigned short Bs[2][128 * LR];

  f32x4 acc[2][4];
#pragma unroll
  for (int i = 0; i < 2; ++i)
#pragma unroll
    for (int j = 0; j < 4; ++j) {
      f32x4 zv = {0.f, 0.f, 0.f, 0.f};
      acc[i][j] = zv;
    }

  const int srow = tid >> 3;
  const int scol = (tid & 7) * 8;

  short8 rvb[3][2];
  f32x4 fva[3][2][2];

  auto LOADK = [&](int kt, int s) {
    int ko = (kt & 3) * 64;
#pragma unroll
    for (int i = 0; i < 2; ++i) {
      int row = srow + i * 64;
      const float* ap = Af + (size_t)(tm * 128 + row) * 256 + ko + scol;
      fva[s][i][0] = *(const f32x4*)(ap);
      fva[s][i][1] = *(const f32x4*)(ap + 4);
      rvb[s][i] = *(const short8*)(Wt + (size_t)(tn * 128 + row) * 256 + kt * 64 + scol);
    }
  };
  auto WRITEK = [&](int s, int buf) {
#pragma unroll
    for (int i = 0; i < 2; ++i) {
      int row = srow + i * 64;
      short8 v;
#pragma unroll
      for (int j = 0; j < 4; ++j) {
        v[j] = (short)f2bf(fva[s][i][0][j]);
        v[j + 4] = (short)f2bf(fva[s][i][1][j]);
      }
      *(short8*)(&As[buf][row * LR + scol]) = v;
      *(short8*)(&Bs[buf][row * LR + scol]) = rvb[s][i];
    }
  };

  LOADK(0, 0);
  LOADK(1, 1);
  LOADK(2, 2);
  WRITEK(0, 0);
  bar_lgkm();

#pragma unroll
  for (int kt = 0; kt < NKT; ++kt) {
    const int cur = kt & 1;
    if (kt + 1 < NKT) WRITEK((kt + 1) % 3, cur ^ 1);
    if (kt + 3 < NKT) LOADK(kt + 3, kt % 3);
#pragma unroll
    for (int kk = 0; kk < 2; ++kk) {
      short8 af[2], bf[4];
#pragma unroll
      for (int mf = 0; mf < 2; ++mf)
        af[mf] = *(const short8*)(&As[cur][(wr * 32 + mf * 16 + (lane & 15)) * LR + kk * 32 + (lane >> 4) * 8]);
#pragma unroll
      for (int nf = 0; nf < 4; ++nf)
        bf[nf] = *(const short8*)(&Bs[cur][(wcl * 64 + nf * 16 + (lane & 15)) * LR + kk * 32 + (lane >> 4) * 8]);
#pragma unroll
      for (int mf = 0; mf < 2; ++mf)
#pragma unroll
        for (int nf = 0; nf < 4; ++nf)
          acc[mf][nf] = __builtin_amdgcn_mfma_f32_16x16x32_bf16(bf[nf], af[mf], acc[mf][nf], 0, 0, 0);
    }
    if (kt + 1 < NKT) bar_lgkm();
  }

  // leaf epilogue: even 16-col groups = z, odd = c (interleaved Wl)
#pragma unroll
  for (int nfp = 0; nfp < 2; ++nfp) {
    int nz = nfp * 2;
    int g = tn * 8 + wcl * 4 + nz;                 // even group id
    int hcq = (g >> 1) * 16 + (lane >> 4) * 4;     // quad base in h-col space
    f32x4 bzv = *(const f32x4*)(bias + 1024 + hcq);
    f32x4 bcv = *(const f32x4*)(bias2 + hcq);
#pragma unroll
    for (int mf = 0; mf < 2; ++mf) {
      int r = tm * 128 + wr * 32 + mf * 16 + (lane & 15);
      int node = 256 + (r >> 6), b = r & 63;
      short4v hv;
      float4 ov;
#pragma unroll
      for (int j = 0; j < 4; ++j) {
        float h = sigmf(acc[mf][nz][j] + bzv[j]) * tanhf_(acc[mf][nz + 1][j] + bcv[j]);
        hv[j] = (short)f2bf(h);
        ((float*)&ov)[j] = h;
      }
      *(short4v*)(hb + (size_t)node * 16384 + b * 256 + hcq) = hv;
      *(float4*)(out + (size_t)b * 262144 + (size_t)(node - 1) * 256 + hcq) = ov;
    }
  }
}

extern "C" void kernel_launch(void* const* d_in, const int* in_sizes, int n_in,
                              void* d_out, int out_size, void* d_ws, size_t ws_size,
                              hipStream_t stream) {
  const float* inputs = (const float*)d_in[0];
  const float* W_gih = (const float*)d_in[3];
  const float* b_gih = (const float*)d_in[4];
  const float* W_glh = (const float*)d_in[5];
  const float* W_grh = (const float*)d_in[6];
  const float* W_cih = (const float*)d_in[7];
  const float* b_cih = (const float*)d_in[8];
  const float* W_clh = (const float*)d_in[9];
  const float* W_crh = (const float*)d_in[10];
  float* out = (float*)d_out;

  char* ws = (char*)d_ws;
  size_t cur = 0;
  auto alloc = [&](size_t bytes) -> char* {
    char* p = ws + cur;
    cur += (bytes + 255) & ~(size_t)255;
    return p;
  };

  // xb holds only internal x rows (0..16383) + pad for tail-block overreads
  unsigned short* xb = (unsigned short*)alloc((size_t)(16384 + 128) * 256 * 2);
  unsigned short* hb = (unsigned short*)alloc((size_t)1025 * 16384 * 2);
  unsigned short* Wg = (unsigned short*)alloc((size_t)1280 * 768 * 2);
  unsigned short* Wc = (unsigned short*)alloc((size_t)256 * 768 * 2);
  unsigned short* Wl = (unsigned short*)alloc((size_t)512 * 256 * 2);

  size_t rem = (ws_size > cur) ? (ws_size - cur) : 0;
  long long rcap = (long long)(rem / (7 * 512 + 64));
  rcap = (rcap / 128) * 128;
  int Rchunk = (int)((rcap < 11008) ? rcap : 11008);  // max internal level = 10944 rows
  if (Rchunk < 128) Rchunk = 128;

  unsigned short* lh  = (unsigned short*)alloc((size_t)Rchunk * 512);
  unsigned short* rh  = (unsigned short*)alloc((size_t)Rchunk * 512);
  unsigned short* a2l = (unsigned short*)alloc((size_t)Rchunk * 512);
  unsigned short* a2r = (unsigned short*)alloc((size_t)Rchunk * 512);
  unsigned short* p1  = (unsigned short*)alloc((size_t)Rchunk * 512);
  unsigned short* p2  = (unsigned short*)alloc((size_t)Rchunk * 512);
  unsigned short* zb  = (unsigned short*)alloc((size_t)Rchunk * 512);

  k_pre<<<5120, 256, 0, stream>>>(inputs, W_gih, W_glh, W_grh, W_cih, W_clh, W_crh,
                                  xb, Wg, Wc, Wl, hb);

  // leaves (nodes 256..1023): 49152 rows, N=512 interleaved, K=256, fp32-direct A
  k_leaf<<<1536, 512, 0, stream>>>(inputs + (size_t)16384 * 256, Wl, b_gih, b_cih, 1536, hb, out);

  // internal levels bottom-up
  static const int LSi[5] = {0, 1, 5, 21, 85};
  static const int LCi[5] = {1, 4, 16, 64, 171};

  for (int d = 4; d >= 0; --d) {
    int rows_lvl = LCi[d] * 64;
    for (int off = 0; off < rows_lvl; off += Rchunk) {
      int rows = rows_lvl - off;
      if (rows > Rchunk) rows = Rchunk;
      int tmn = (rows + 127) / 128;
      int pgrid = (rows * 32 + 255) / 256;
      k_prep<<<pgrid, 256, 0, stream>>>(hb, lh, rh, rows, off, LSi[d]);
      const unsigned short* xseg = xb + (size_t)(LSi[d] * 64 + off) * 256;
      int nwg_g = tmn * 10;
      k_gates<<<nwg_g, 512, 0, stream>>>(xseg, lh, rh, Wg, b_gih, rows, off, LSi[d], nwg_g,
                                         lh, rh, a2l, a2r, p1, p2, zb);
      int nwg_c = tmn * 2;
      k_cell<<<nwg_c, 512, 0, stream>>>(xseg, a2l, a2r, Wc, b_cih, rows, off, LSi[d], nwg_c,
                                        p1, p2, zb, hb, out);
    }
  }
}

// Round 12
// 300.298 us; speedup vs baseline: 1.0623x; 1.0623x over previous
//
#include <hip/hip_runtime.h>

// DTTreeGRU: L=1024, B=64, D=256, H=256, K=4 (tree arity)
// Heap tree: internal nodes 0..255, leaves 256..1023 (children 4n+1..4n+4).
// Internal levels (bottom-up): starts {0,1,5,21,85}, counts {1,4,16,64,171}.
// Leaves: lh=rh=0 -> h = sigmoid(x@Wz^T+bz) * tanh(x@Wc^T+bc): one GEMM over
// interleaved Wl (512 x 256; 16-col z/c groups so z,c pair within one wave).
//
// r12: m97-faithful wave decomposition — 256 threads, 4 waves (2x2), wave
// owns 64x64, acc[4][4] = 32 MFMA/wave/barrier (r4-r11 ran 8 waves with
// acc[2][4] = 16 MFMA/barrier — half the compute per sync; never isolated).
// Rest = r10 pipeline: PF2 reg-staged dbuf LDS (LR=72 pad), one lgkm-only
// barrier per K-step, swapped-operand MFMA (C^T lane map, vector epilogues).

#define L_TOT 1024

typedef __attribute__((ext_vector_type(8))) short short8;
typedef __attribute__((ext_vector_type(4))) short short4v;
typedef __attribute__((ext_vector_type(4))) float f32x4;

static __device__ __forceinline__ float bf2f(unsigned short u) {
  unsigned int x = ((unsigned int)u) << 16;
  return __builtin_bit_cast(float, x);
}
static __device__ __forceinline__ unsigned short f2bf(float f) {
  unsigned int u = __builtin_bit_cast(unsigned int, f);
  u += 0x7fffu + ((u >> 16) & 1u);
  return (unsigned short)(u >> 16);
}
static __device__ __forceinline__ float sigmf(float x) { return 1.0f / (1.0f + __expf(-x)); }
static __device__ __forceinline__ float tanhf_(float x) { return 2.0f / (1.0f + __expf(-2.0f * x)) - 1.0f; }

// lgkm-only barrier: LDS ops visible, global loads stay in flight
static __device__ __forceinline__ void bar_lgkm() {
  asm volatile("s_waitcnt lgkmcnt(0)" ::: "memory");
  __builtin_amdgcn_s_barrier();
  __builtin_amdgcn_sched_barrier(0);
}

// bijective XCD swizzle (m204): contiguous logical range per XCD
static __device__ __forceinline__ int swz_t(int orig, int nwg) {
  int q = nwg >> 3, r = nwg & 7, x = orig & 7, s = orig >> 3;
  return (x < r ? x * (q + 1) : r * (q + 1) + (x - r) * q) + s;
}

// ---- prologue: convert INTERNAL x rows -> bf16, build weights, zero pad ----
__global__ __launch_bounds__(256) void k_pre(
    const float* __restrict__ in,
    const float* __restrict__ Wgih, const float* __restrict__ Wglh, const float* __restrict__ Wgrh,
    const float* __restrict__ Wcih, const float* __restrict__ Wclh, const float* __restrict__ Wcrh,
    unsigned short* __restrict__ xb, unsigned short* __restrict__ Wg,
    unsigned short* __restrict__ Wc, unsigned short* __restrict__ Wl,
    unsigned short* __restrict__ hb) {
  int t = blockIdx.x * 256 + threadIdx.x;
  if (t < 524288) {
    const float* s = in + (size_t)t * 8;
    short8 v;
#pragma unroll
    for (int j = 0; j < 8; ++j) v[j] = (short)f2bf(s[j]);
    *(short8*)(xb + (size_t)t * 8) = v;
  }
  const int NG = 1280 * 768;
  const int NC = 256 * 768;
  const int NL = 512 * 256;
  if (t < NG) {
    int g = t / 768, k = t % 768;
    float v = (k < 256) ? Wgih[g * 256 + k] : ((k < 512) ? Wglh[g * 256 + k - 256] : Wgrh[g * 256 + k - 512]);
    Wg[t] = f2bf(v);
  } else if (t < NG + NC) {
    int t2 = t - NG;
    int g = t2 / 768, k = t2 % 768;
    float v = (k < 256) ? Wcih[g * 256 + k] : ((k < 512) ? Wclh[g * 256 + k - 256] : Wcrh[g * 256 + k - 512]);
    Wc[t2] = f2bf(v);
  } else if (t < NG + NC + NL) {
    int t2 = t - NG - NC;
    int n = t2 >> 8, k = t2 & 255;
    int g = n >> 4;
    int hc = (g >> 1) * 16 + (n & 15);
    float v = (g & 1) ? Wcih[hc * 256 + k] : Wgih[(1024 + hc) * 256 + k];
    Wl[t2] = f2bf(v);
  }
  if (t < 16384) hb[(size_t)1024 * 16384 + t] = 0;
}

// ---- per-level: lh = h[c0]+h[c1], rh = h[c2]+h[c3]; 8 elems/thread ----
__global__ __launch_bounds__(256) void k_prep(const unsigned short* __restrict__ hb,
                                              unsigned short* __restrict__ lh,
                                              unsigned short* __restrict__ rh,
                                              int rows, int row_off, int lvl_start) {
  int t = blockIdx.x * 256 + threadIdx.x;
  if (t >= rows * 32) return;
  int r = t >> 5, k8 = (t & 31) << 3;
  int gr = row_off + r;
  int node = lvl_start + (gr >> 6);
  int b = gr & 63;
  int cb = 4 * node + 1;
  int c0 = cb, c1 = cb + 1, c2 = cb + 2, c3 = cb + 3;
  c0 = (c0 < L_TOT) ? c0 : L_TOT;
  c1 = (c1 < L_TOT) ? c1 : L_TOT;
  c2 = (c2 < L_TOT) ? c2 : L_TOT;
  c3 = (c3 < L_TOT) ? c3 : L_TOT;
  const short8 v0 = *(const short8*)(hb + (size_t)c0 * 16384 + b * 256 + k8);
  const short8 v1 = *(const short8*)(hb + (size_t)c1 * 16384 + b * 256 + k8);
  const short8 v2 = *(const short8*)(hb + (size_t)c2 * 16384 + b * 256 + k8);
  const short8 v3 = *(const short8*)(hb + (size_t)c3 * 16384 + b * 256 + k8);
  short8 ol, orr;
#pragma unroll
  for (int j = 0; j < 8; ++j) {
    ol[j] = (short)f2bf(bf2f((unsigned short)v0[j]) + bf2f((unsigned short)v1[j]));
    orr[j] = (short)f2bf(bf2f((unsigned short)v2[j]) + bf2f((unsigned short)v3[j]));
  }
  *(short8*)(lh + (size_t)r * 256 + k8) = ol;
  *(short8*)(rh + (size_t)r * 256 + k8) = orr;
}

// ---- 4-wave reg-staged PF2 dbuf MFMA GEMM, 128x128 tile, acc[4][4] ----
// Swapped-operand MFMA: acc holds C^T fragments (m = lane&15, n = quad).
// EPI 0: gates (N=1280, K=768): sigmoid + vector scatter a2l/a2r/p1/p2/zb
// EPI 1: cell  (N=256,  K=768): tanh + hidden -> hb (bf16)
// EPI 2: leaf  (N=512 interleaved Wl, K=256): fp32-direct A; sig*tanh -> hb
template <int EPI>
static __device__ __forceinline__ void gemm_body(
    const float* __restrict__ Af,
    const unsigned short* __restrict__ Aseg0,
    const unsigned short* __restrict__ Aseg1,
    const unsigned short* __restrict__ Aseg2,
    const unsigned short* __restrict__ Wt, const float* __restrict__ bias,
    const float* __restrict__ bias2,
    int rows, int row_off, int lvl_start, int NT, int nwg,
    const unsigned short* __restrict__ lh, const unsigned short* __restrict__ rh,
    unsigned short* __restrict__ a2l, unsigned short* __restrict__ a2r,
    unsigned short* __restrict__ p1, unsigned short* __restrict__ p2,
    unsigned short* __restrict__ zb, unsigned short* __restrict__ hb) {
  constexpr int NKT = (EPI == 2) ? 4 : 12;         // K-steps of 64
  constexpr int WSTRIDE = (EPI == 2) ? 256 : 768;  // B row stride
  constexpr int LR = 72;                           // padded LDS row; 144 B = 9*16B
  int t = swz_t(blockIdx.x, nwg);
  int tm = t / NT, tn = t % NT;
  const int tid = threadIdx.x, lane = tid & 63, wave = tid >> 6;
  const int wr = wave >> 1, wcl = wave & 1;  // 2x2 wave grid; wave owns 64x64

  __shared__ unsigned short As[2][128 * LR];
  __shared__ unsigned short Bs[2][128 * LR];

  f32x4 acc[4][4];
#pragma unroll
  for (int i = 0; i < 4; ++i)
#pragma unroll
    for (int j = 0; j < 4; ++j) {
      f32x4 zv = {0.f, 0.f, 0.f, 0.f};
      acc[i][j] = zv;
    }

  const unsigned short* segs[3] = {Aseg0, Aseg1, Aseg2};

  // staging: 1024 chunks of 8 bf16 per array; thread covers chunks tid+256*i
  short8 rva[2][4], rvb[2][4];   // PF2 sets, statically indexed
  f32x4 fva[2][4][2];            // leaf fp32 A staging

  auto LOADK = [&](int kt, int s) {
    int ko = (kt & 3) * 64;
#pragma unroll
    for (int i = 0; i < 4; ++i) {
      int ch = tid + 256 * i;
      int row = ch >> 3;
      int co = (ch & 7) * 8;
      if (EPI == 2) {
        const float* ap = Af + (size_t)(tm * 128 + row) * 256 + ko + co;
        fva[s][i][0] = *(const f32x4*)(ap);
        fva[s][i][1] = *(const f32x4*)(ap + 4);
      } else {
        const unsigned short* segp = segs[kt >> 2];
        rva[s][i] = *(const short8*)(segp + (size_t)(tm * 128 + row) * 256 + ko + co);
      }
      rvb[s][i] = *(const short8*)(Wt + (size_t)(tn * 128 + row) * WSTRIDE + kt * 64 + co);
    }
  };
  auto WRITEK = [&](int s, int buf) {
#pragma unroll
    for (int i = 0; i < 4; ++i) {
      int ch = tid + 256 * i;
      int row = ch >> 3;
      int co = (ch & 7) * 8;
      short8 v;
      if (EPI == 2) {
#pragma unroll
        for (int j = 0; j < 4; ++j) {
          v[j] = (short)f2bf(fva[s][i][0][j]);
          v[j + 4] = (short)f2bf(fva[s][i][1][j]);
        }
      } else {
        v = rva[s][i];
      }
      *(short8*)(&As[buf][row * LR + co]) = v;
      *(short8*)(&Bs[buf][row * LR + co]) = rvb[s][i];
    }
  };

  LOADK(0, 0);
  if (NKT > 1) LOADK(1, 1);
  WRITEK(0, 0);
  bar_lgkm();

#pragma unroll
  for (int kt = 0; kt < NKT; ++kt) {
    const int cur = kt & 1;
    if (kt + 1 < NKT) WRITEK((kt + 1) & 1, cur ^ 1);  // counted vmcnt (tile kt+1)
    if (kt + 2 < NKT) LOADK(kt + 2, kt & 1);          // refill freed set
#pragma unroll
    for (int kk = 0; kk < 2; ++kk) {
      short8 af[4], bf[4];
#pragma unroll
      for (int mf = 0; mf < 4; ++mf)
        af[mf] = *(const short8*)(&As[cur][(wr * 64 + mf * 16 + (lane & 15)) * LR + kk * 32 + (lane >> 4) * 8]);
#pragma unroll
      for (int nf = 0; nf < 4; ++nf)
        bf[nf] = *(const short8*)(&Bs[cur][(wcl * 64 + nf * 16 + (lane & 15)) * LR + kk * 32 + (lane >> 4) * 8]);
      // swapped operands: acc = W-frag x A-frag = C^T fragment
#pragma unroll
      for (int mf = 0; mf < 4; ++mf)
#pragma unroll
        for (int nf = 0; nf < 4; ++nf)
          acc[mf][nf] = __builtin_amdgcn_mfma_f32_16x16x32_bf16(bf[nf], af[mf], acc[mf][nf], 0, 0, 0);
    }
    if (kt + 1 < NKT) bar_lgkm();
  }

  // ---- epilogue: C^T lane map: m-row = ..+(lane&15), n-col quad = ..+(lane>>4)*4+j ----
  if (EPI == 2) {
    // leaf: even 16-col groups = z, odd = c (interleaved Wl): pairs (nf, nf+1)
#pragma unroll
    for (int nfp = 0; nfp < 2; ++nfp) {
      int nz = nfp * 2;
      int g = tn * 8 + wcl * 4 + nz;                 // even group id
      int hcq = (g >> 1) * 16 + (lane >> 4) * 4;     // quad base in h-col space
      f32x4 bzv = *(const f32x4*)(bias + 1024 + hcq);
      f32x4 bcv = *(const f32x4*)(bias2 + hcq);
#pragma unroll
      for (int mf = 0; mf < 4; ++mf) {
        int r = tm * 128 + wr * 64 + mf * 16 + (lane & 15);
        int node = 256 + (r >> 6), b = r & 63;
        short4v hv;
#pragma unroll
        for (int j = 0; j < 4; ++j) {
          float h = sigmf(acc[mf][nz][j] + bzv[j]) * tanhf_(acc[mf][nz + 1][j] + bcv[j]);
          hv[j] = (short)f2bf(h);
        }
        *(short4v*)(hb + (size_t)node * 16384 + b * 256 + hcq) = hv;
      }
    }
    return;
  }
#pragma unroll
  for (int nf = 0; nf < 4; ++nf) {
    int colq = tn * 128 + wcl * 64 + nf * 16 + (lane >> 4) * 4;
    f32x4 bsv = *(const f32x4*)(bias + colq);
    if (EPI == 0) {
      int ck = colq >> 8;        // uniform per block
      int gcq = colq & 255;
#pragma unroll
      for (int mf = 0; mf < 4; ++mf) {
        int r = tm * 128 + wr * 64 + mf * 16 + (lane & 15);
        if (r < rows) {
          size_t idx = (size_t)r * 256 + gcq;
          f32x4 s;
#pragma unroll
          for (int j = 0; j < 4; ++j) s[j] = sigmf(acc[mf][nf][j] + bsv[j]);
          short4v res;
          if (ck == 4) {
#pragma unroll
            for (int j = 0; j < 4; ++j) res[j] = (short)f2bf(s[j]);
            *(short4v*)(zb + idx) = res;
          } else {
            const unsigned short* src = (ck == 0 || ck == 2) ? lh : rh;
            short4v hv = *(const short4v*)(src + idx);
#pragma unroll
            for (int j = 0; j < 4; ++j) res[j] = (short)f2bf(s[j] * bf2f((unsigned short)hv[j]));
            if (ck == 0)      *(short4v*)(a2l + idx) = res;
            else if (ck == 1) *(short4v*)(a2r + idx) = res;
            else if (ck == 2) *(short4v*)(p1 + idx) = res;
            else              *(short4v*)(p2 + idx) = res;
          }
        }
      }
    } else {
#pragma unroll
      for (int mf = 0; mf < 4; ++mf) {
        int r = tm * 128 + wr * 64 + mf * 16 + (lane & 15);
        if (r < rows) {
          size_t idx = (size_t)r * 256 + colq;
          short4v p1v = *(const short4v*)(p1 + idx);
          short4v p2v = *(const short4v*)(p2 + idx);
          short4v zbv = *(const short4v*)(zb + idx);
          int gr = row_off + r;
          int node = lvl_start + (gr >> 6);
          int b = gr & 63;
          short4v hv;
#pragma unroll
          for (int j = 0; j < 4; ++j) {
            float cell = tanhf_(acc[mf][nf][j] + bsv[j]);
            float hid = bf2f((unsigned short)p1v[j]) + bf2f((unsigned short)p2v[j]) +
                        bf2f((unsigned short)zbv[j]) * cell;
            hv[j] = (short)f2bf(hid);
          }
          *(short4v*)(hb + (size_t)node * 16384 + b * 256 + colq) = hv;
        }
      }
    }
  }
}

__global__ __launch_bounds__(256, 2) void k_gates(
    const unsigned short* __restrict__ A0, const unsigned short* __restrict__ A1,
    const unsigned short* __restrict__ A2, const unsigned short* __restrict__ Wt,
    const float* __restrict__ bias, int rows, int row_off, int lvl_start, int nwg,
    const unsigned short* __restrict__ lh, const unsigned short* __restrict__ rh,
    unsigned short* __restrict__ a2l, unsigned short* __restrict__ a2r,
    unsigned short* __restrict__ p1, unsigned short* __restrict__ p2,
    unsigned short* __restrict__ zb) {
  gemm_body<0>(nullptr, A0, A1, A2, Wt, bias, nullptr, rows, row_off, lvl_start, 10, nwg,
               lh, rh, a2l, a2r, p1, p2, zb, nullptr);
}

__global__ __launch_bounds__(256, 2) void k_cell(
    const unsigned short* __restrict__ A0, const unsigned short* __restrict__ A1,
    const unsigned short* __restrict__ A2, const unsigned short* __restrict__ Wt,
    const float* __restrict__ bias, int rows, int row_off, int lvl_start, int nwg,
    const unsigned short* __restrict__ p1, const unsigned short* __restrict__ p2,
    const unsigned short* __restrict__ zb, unsigned short* __restrict__ hb) {
  gemm_body<1>(nullptr, A0, A1, A2, Wt, bias, nullptr, rows, row_off, lvl_start, 2, nwg,
               nullptr, nullptr, nullptr, nullptr, (unsigned short*)p1,
               (unsigned short*)p2, (unsigned short*)zb, hb);
}

__global__ __launch_bounds__(256, 2) void k_leaf(
    const float* __restrict__ X, const unsigned short* __restrict__ Wl,
    const float* __restrict__ bg, const float* __restrict__ bc, int nwg,
    unsigned short* __restrict__ hb) {
  gemm_body<2>(X, nullptr, nullptr, nullptr, Wl, bg, bc, 49152, 0, 0, 4, nwg,
               nullptr, nullptr, nullptr, nullptr, nullptr, nullptr, nullptr, hb);
}

// ---- final output from hb: coalesced fp32 writes ----
// out[b,i,k] = h[(i+1)%1024][b][k]; out2[b,k] = h[0][b][k]
__global__ __launch_bounds__(256) void k_write_out(const unsigned short* __restrict__ hb,
                                                   float* __restrict__ out) {
  long long t = (long long)blockIdx.x * 256 + threadIdx.x;
  long long e = t * 8;
  const long long main_n = 16777216LL;  // 64*1024*256
  if (e < main_n) {
    int b = (int)(e >> 18);
    int rem = (int)(e & 262143);
    int i = rem >> 8;
    int k = rem & 255;
    int node = (i + 1) & 1023;
    short8 v = *(const short8*)(hb + (size_t)node * 16384 + b * 256 + k);
    float4 o0, o1;
    o0.x = bf2f((unsigned short)v[0]); o0.y = bf2f((unsigned short)v[1]);
    o0.z = bf2f((unsigned short)v[2]); o0.w = bf2f((unsigned short)v[3]);
    o1.x = bf2f((unsigned short)v[4]); o1.y = bf2f((unsigned short)v[5]);
    o1.z = bf2f((unsigned short)v[6]); o1.w = bf2f((unsigned short)v[7]);
    *(float4*)(out + e) = o0;
    *(float4*)(out + e + 4) = o1;
  } else if (e < main_n + 16384) {
    int e2 = (int)(e - main_n);
    int b = e2 >> 8, k = e2 & 255;
    short8 v = *(const short8*)(hb + (size_t)b * 256 + k);  // node 0
    float4 o0, o1;
    o0.x = bf2f((unsigned short)v[0]); o0.y = bf2f((unsigned short)v[1]);
    o0.z = bf2f((unsigned short)v[2]); o0.w = bf2f((unsigned short)v[3]);
    o1.x = bf2f((unsigned short)v[4]); o1.y = bf2f((unsigned short)v[5]);
    o1.z = bf2f((unsigned short)v[6]); o1.w = bf2f((unsigned short)v[7]);
    *(float4*)(out + e) = o0;
    *(float4*)(out + e + 4) = o1;
  }
}

extern "C" void kernel_launch(void* const* d_in, const int* in_sizes, int n_in,
                              void* d_out, int out_size, void* d_ws, size_t ws_size,
                              hipStream_t stream) {
  const float* inputs = (const float*)d_in[0];
  const float* W_gih = (const float*)d_in[3];
  const float* b_gih = (const float*)d_in[4];
  const float* W_glh = (const float*)d_in[5];
  const float* W_grh = (const float*)d_in[6];
  const float* W_cih = (const float*)d_in[7];
  const float* b_cih = (const float*)d_in[8];
  const float* W_clh = (const float*)d_in[9];
  const float* W_crh = (const float*)d_in[10];
  float* out = (float*)d_out;

  char* ws = (char*)d_ws;
  size_t cur = 0;
  auto alloc = [&](size_t bytes) -> char* {
    char* p = ws + cur;
    cur += (bytes + 255) & ~(size_t)255;
    return p;
  };

  // xb holds only internal x rows (0..16383) + pad for tail-block overreads
  unsigned short* xb = (unsigned short*)alloc((size_t)(16384 + 128) * 256 * 2);
  unsigned short* hb = (unsigned short*)alloc((size_t)1025 * 16384 * 2);
  unsigned short* Wg = (unsigned short*)alloc((size_t)1280 * 768 * 2);
  unsigned short* Wc = (unsigned short*)alloc((size_t)256 * 768 * 2);
  unsigned short* Wl = (unsigned short*)alloc((size_t)512 * 256 * 2);

  size_t rem = (ws_size > cur) ? (ws_size - cur) : 0;
  long long rcap = (long long)(rem / (7 * 512 + 64));
  rcap = (rcap / 128) * 128;
  int Rchunk = (int)((rcap < 11008) ? rcap : 11008);  // max internal level = 10944 rows
  if (Rchunk < 128) Rchunk = 128;

  unsigned short* lh  = (unsigned short*)alloc((size_t)Rchunk * 512);
  unsigned short* rh  = (unsigned short*)alloc((size_t)Rchunk * 512);
  unsigned short* a2l = (unsigned short*)alloc((size_t)Rchunk * 512);
  unsigned short* a2r = (unsigned short*)alloc((size_t)Rchunk * 512);
  unsigned short* p1  = (unsigned short*)alloc((size_t)Rchunk * 512);
  unsigned short* p2  = (unsigned short*)alloc((size_t)Rchunk * 512);
  unsigned short* zb  = (unsigned short*)alloc((size_t)Rchunk * 512);

  k_pre<<<5120, 256, 0, stream>>>(inputs, W_gih, W_glh, W_grh, W_cih, W_clh, W_crh,
                                  xb, Wg, Wc, Wl, hb);

  // leaves (nodes 256..1023): 49152 rows, N=512 interleaved, K=256, fp32-direct A
  k_leaf<<<1536, 256, 0, stream>>>(inputs + (size_t)16384 * 256, Wl, b_gih, b_cih, 1536, hb);

  // internal levels bottom-up
  static const int LSi[5] = {0, 1, 5, 21, 85};
  static const int LCi[5] = {1, 4, 16, 64, 171};

  for (int d = 4; d >= 0; --d) {
    int rows_lvl = LCi[d] * 64;
    for (int off = 0; off < rows_lvl; off += Rchunk) {
      int rows = rows_lvl - off;
      if (rows > Rchunk) rows = Rchunk;
      int tmn = (rows + 127) / 128;
      int pgrid = (rows * 32 + 255) / 256;
      k_prep<<<pgrid, 256, 0, stream>>>(hb, lh, rh, rows, off, LSi[d]);
      const unsigned short* xseg = xb + (size_t)(LSi[d] * 64 + off) * 256;
      int nwg_g = tmn * 10;
      k_gates<<<nwg_g, 256, 0, stream>>>(xseg, lh, rh, Wg, b_gih, rows, off, LSi[d], nwg_g,
                                         lh, rh, a2l, a2r, p1, p2, zb);
      int nwg_c = tmn * 2;
      k_cell<<<nwg_c, 256, 0, stream>>>(xseg, a2l, a2r, Wc, b_cih, rows, off, LSi[d], nwg_c,
                                        p1, p2, zb, hb);
    }
  }

  k_write_out<<<8200, 256, 0, stream>>>(hb, out);
}

// Round 13
// 279.477 us; speedup vs baseline: 1.1415x; 1.0745x over previous
//
#include <hip/hip_runtime.h>

// DTTreeGRU: L=1024, B=64, D=256, H=256, K=4 (tree arity)
// Heap tree: internal nodes 0..255, leaves 256..1023 (children 4n+1..4n+4).
// Internal levels (bottom-up): starts {0,1,5,21,85}, counts {1,4,16,64,171}.
// Leaves: lh=rh=0 -> h = sigmoid(x@Wz^T+bz) * tanh(x@Wc^T+bc): one GEMM over
// interleaved Wl (512 x 256; 16-col z/c groups so z,c pair within one wave).
//
// r13: r8/r10 8-wave config (proven best) with staging switched from
// reg-staged+padded-LDS to global_load_lds + LINEAR LDS + swizzle pair
// (rule #21): global source pre-swizzled slot^=(row&7), ds_read applies the
// same XOR -> conflict-free reads (2-way only) AND async direct-to-LDS
// staging (m151: reg-staging costs ~26%). One vm+lgkm drain + barrier per
// K-step; STAGE issued after the barrier (full compute phase in flight).
// Leaf keeps r10 reg-staged fp32-A body. Swapped-operand C^T epilogues.

#define L_TOT 1024

typedef __attribute__((ext_vector_type(8))) short short8;
typedef __attribute__((ext_vector_type(4))) short short4v;
typedef __attribute__((ext_vector_type(4))) float f32x4;

static __device__ __forceinline__ float bf2f(unsigned short u) {
  unsigned int x = ((unsigned int)u) << 16;
  return __builtin_bit_cast(float, x);
}
static __device__ __forceinline__ unsigned short f2bf(float f) {
  unsigned int u = __builtin_bit_cast(unsigned int, f);
  u += 0x7fffu + ((u >> 16) & 1u);
  return (unsigned short)(u >> 16);
}
static __device__ __forceinline__ float sigmf(float x) { return 1.0f / (1.0f + __expf(-x)); }
static __device__ __forceinline__ float tanhf_(float x) { return 2.0f / (1.0f + __expf(-2.0f * x)) - 1.0f; }

// async global->LDS, 16B per lane; lds base must be wave-uniform
static __device__ __forceinline__ void stage16(void* lds, const void* g) {
  __builtin_amdgcn_global_load_lds(
      (const __attribute__((address_space(1))) unsigned int*)g,
      (__attribute__((address_space(3))) unsigned int*)lds, 16, 0, 0);
}

// full drain + barrier (one per K-step; stages have a whole phase in flight)
static __device__ __forceinline__ void bar_full() {
  asm volatile("s_waitcnt vmcnt(0) lgkmcnt(0)" ::: "memory");
  __builtin_amdgcn_s_barrier();
  __builtin_amdgcn_sched_barrier(0);
}
static __device__ __forceinline__ void bar_lgkm() {
  asm volatile("s_waitcnt lgkmcnt(0)" ::: "memory");
  __builtin_amdgcn_s_barrier();
  __builtin_amdgcn_sched_barrier(0);
}

// bijective XCD swizzle (m204): contiguous logical range per XCD
static __device__ __forceinline__ int swz_t(int orig, int nwg) {
  int q = nwg >> 3, r = nwg & 7, x = orig & 7, s = orig >> 3;
  return (x < r ? x * (q + 1) : r * (q + 1) + (x - r) * q) + s;
}

// ---- prologue: convert INTERNAL x rows -> bf16, build weights, zero pad ----
__global__ __launch_bounds__(256) void k_pre(
    const float* __restrict__ in,
    const float* __restrict__ Wgih, const float* __restrict__ Wglh, const float* __restrict__ Wgrh,
    const float* __restrict__ Wcih, const float* __restrict__ Wclh, const float* __restrict__ Wcrh,
    unsigned short* __restrict__ xb, unsigned short* __restrict__ Wg,
    unsigned short* __restrict__ Wc, unsigned short* __restrict__ Wl,
    unsigned short* __restrict__ hb) {
  int t = blockIdx.x * 256 + threadIdx.x;
  if (t < 524288) {
    const float* s = in + (size_t)t * 8;
    short8 v;
#pragma unroll
    for (int j = 0; j < 8; ++j) v[j] = (short)f2bf(s[j]);
    *(short8*)(xb + (size_t)t * 8) = v;
  }
  const int NG = 1280 * 768;
  const int NC = 256 * 768;
  const int NL = 512 * 256;
  if (t < NG) {
    int g = t / 768, k = t % 768;
    float v = (k < 256) ? Wgih[g * 256 + k] : ((k < 512) ? Wglh[g * 256 + k - 256] : Wgrh[g * 256 + k - 512]);
    Wg[t] = f2bf(v);
  } else if (t < NG + NC) {
    int t2 = t - NG;
    int g = t2 / 768, k = t2 % 768;
    float v = (k < 256) ? Wcih[g * 256 + k] : ((k < 512) ? Wclh[g * 256 + k - 256] : Wcrh[g * 256 + k - 512]);
    Wc[t2] = f2bf(v);
  } else if (t < NG + NC + NL) {
    int t2 = t - NG - NC;
    int n = t2 >> 8, k = t2 & 255;
    int g = n >> 4;
    int hc = (g >> 1) * 16 + (n & 15);
    float v = (g & 1) ? Wcih[hc * 256 + k] : Wgih[(1024 + hc) * 256 + k];
    Wl[t2] = f2bf(v);
  }
  if (t < 16384) hb[(size_t)1024 * 16384 + t] = 0;
}

// ---- per-level: lh = h[c0]+h[c1], rh = h[c2]+h[c3]; 8 elems/thread ----
__global__ __launch_bounds__(256) void k_prep(const unsigned short* __restrict__ hb,
                                              unsigned short* __restrict__ lh,
                                              unsigned short* __restrict__ rh,
                                              int rows, int row_off, int lvl_start) {
  int t = blockIdx.x * 256 + threadIdx.x;
  if (t >= rows * 32) return;
  int r = t >> 5, k8 = (t & 31) << 3;
  int gr = row_off + r;
  int node = lvl_start + (gr >> 6);
  int b = gr & 63;
  int cb = 4 * node + 1;
  int c0 = cb, c1 = cb + 1, c2 = cb + 2, c3 = cb + 3;
  c0 = (c0 < L_TOT) ? c0 : L_TOT;
  c1 = (c1 < L_TOT) ? c1 : L_TOT;
  c2 = (c2 < L_TOT) ? c2 : L_TOT;
  c3 = (c3 < L_TOT) ? c3 : L_TOT;
  const short8 v0 = *(const short8*)(hb + (size_t)c0 * 16384 + b * 256 + k8);
  const short8 v1 = *(const short8*)(hb + (size_t)c1 * 16384 + b * 256 + k8);
  const short8 v2 = *(const short8*)(hb + (size_t)c2 * 16384 + b * 256 + k8);
  const short8 v3 = *(const short8*)(hb + (size_t)c3 * 16384 + b * 256 + k8);
  short8 ol, orr;
#pragma unroll
  for (int j = 0; j < 8; ++j) {
    ol[j] = (short)f2bf(bf2f((unsigned short)v0[j]) + bf2f((unsigned short)v1[j]));
    orr[j] = (short)f2bf(bf2f((unsigned short)v2[j]) + bf2f((unsigned short)v3[j]));
  }
  *(short8*)(lh + (size_t)r * 256 + k8) = ol;
  *(short8*)(rh + (size_t)r * 256 + k8) = orr;
}

// ---- stage16-swizzle MFMA GEMM: 128x128 tile, 8 waves, linear dbuf LDS ----
// LDS chunk (row, slot) holds global (row, slot^(row&7)); ds_read XORs back.
// Swapped-operand MFMA: acc holds C^T fragments (m = lane&15, n = quad).
// EPI 0: gates (N=1280, K=768): sigmoid + vector scatter a2l/a2r/p1/p2/zb
// EPI 1: cell  (N=256,  K=768): tanh + hidden -> hb (bf16)
template <int EPI>
static __device__ __forceinline__ void gemm_stg(
    const unsigned short* __restrict__ Aseg0,
    const unsigned short* __restrict__ Aseg1,
    const unsigned short* __restrict__ Aseg2,
    const unsigned short* __restrict__ Wt, const float* __restrict__ bias,
    int rows, int row_off, int lvl_start, int NT, int nwg,
    const unsigned short* __restrict__ lh, const unsigned short* __restrict__ rh,
    unsigned short* __restrict__ a2l, unsigned short* __restrict__ a2r,
    unsigned short* __restrict__ p1, unsigned short* __restrict__ p2,
    unsigned short* __restrict__ zb, unsigned short* __restrict__ hb) {
  constexpr int NKT = 12;   // K-steps of 64 (K=768)
  constexpr int WSTRIDE = 768;
  int t = swz_t(blockIdx.x, nwg);
  int tm = t / NT, tn = t % NT;
  const int tid = threadIdx.x, lane = tid & 63, wave = tid >> 6;
  const int wr = wave >> 1, wcl = wave & 1;  // 4x2 wave grid; wave owns 32x64

  __shared__ unsigned short As[2][128 * 64];   // linear; 16 KB each
  __shared__ unsigned short Bs[2][128 * 64];   // total 64 KB -> 2 blocks/CU

  f32x4 acc[2][4];
#pragma unroll
  for (int i = 0; i < 2; ++i)
#pragma unroll
    for (int j = 0; j < 4; ++j) {
      f32x4 zv = {0.f, 0.f, 0.f, 0.f};
      acc[i][j] = zv;
    }

  const unsigned short* segs[3] = {Aseg0, Aseg1, Aseg2};

  // per-lane swizzled source geometry (chunk = wave*128 + i*64 + lane)
  auto STAGE = [&](int kt, int buf) {
    const unsigned short* segp = segs[kt >> 2];
    int ko = (kt & 3) * 64;
#pragma unroll
    for (int i = 0; i < 2; ++i) {
      int c0 = wave * 128 + i * 64;        // wave-uniform base chunk
      int c = c0 + lane;
      int row = c >> 3;
      int so = ((c & 7) ^ (row & 7)) * 8;  // pre-swizzled source slot
      stage16(&As[buf][c0 * 8], segp + (size_t)(tm * 128 + row) * 256 + ko + so);
      stage16(&Bs[buf][c0 * 8], Wt + (size_t)(tn * 128 + row) * WSTRIDE + kt * 64 + so);
    }
  };

  STAGE(0, 0);

#pragma unroll
  for (int kt = 0; kt < NKT; ++kt) {
    const int cur = kt & 1;
    bar_full();                               // drains my stages; all waves sync
    if (kt + 1 < NKT) STAGE(kt + 1, cur ^ 1); // full compute phase in flight
#pragma unroll
    for (int kk = 0; kk < 2; ++kk) {
      short8 af[2], bf[4];
#pragma unroll
      for (int mf = 0; mf < 2; ++mf) {
        int ra = wr * 32 + mf * 16 + (lane & 15);
        int sl = (kk * 4 + (lane >> 4)) ^ (ra & 7);
        af[mf] = *(const short8*)(&As[cur][ra * 64 + sl * 8]);
      }
#pragma unroll
      for (int nf = 0; nf < 4; ++nf) {
        int rb = wcl * 64 + nf * 16 + (lane & 15);
        int sl = (kk * 4 + (lane >> 4)) ^ (rb & 7);
        bf[nf] = *(const short8*)(&Bs[cur][rb * 64 + sl * 8]);
      }
      // swapped operands: acc = W-frag x A-frag = C^T fragment
#pragma unroll
      for (int mf = 0; mf < 2; ++mf)
#pragma unroll
        for (int nf = 0; nf < 4; ++nf)
          acc[mf][nf] = __builtin_amdgcn_mfma_f32_16x16x32_bf16(bf[nf], af[mf], acc[mf][nf], 0, 0, 0);
    }
  }

  // ---- epilogue: C^T lane map: m-row = ..+(lane&15), n-col quad = ..+(lane>>4)*4+j ----
#pragma unroll
  for (int nf = 0; nf < 4; ++nf) {
    int colq = tn * 128 + wcl * 64 + nf * 16 + (lane >> 4) * 4;
    f32x4 bsv = *(const f32x4*)(bias + colq);
    if (EPI == 0) {
      int ck = colq >> 8;        // uniform per block
      int gcq = colq & 255;
#pragma unroll
      for (int mf = 0; mf < 2; ++mf) {
        int r = tm * 128 + wr * 32 + mf * 16 + (lane & 15);
        if (r < rows) {
          size_t idx = (size_t)r * 256 + gcq;
          f32x4 s;
#pragma unroll
          for (int j = 0; j < 4; ++j) s[j] = sigmf(acc[mf][nf][j] + bsv[j]);
          short4v res;
          if (ck == 4) {
#pragma unroll
            for (int j = 0; j < 4; ++j) res[j] = (short)f2bf(s[j]);
            *(short4v*)(zb + idx) = res;
          } else {
            const unsigned short* src = (ck == 0 || ck == 2) ? lh : rh;
            short4v hv = *(const short4v*)(src + idx);
#pragma unroll
            for (int j = 0; j < 4; ++j) res[j] = (short)f2bf(s[j] * bf2f((unsigned short)hv[j]));
            if (ck == 0)      *(short4v*)(a2l + idx) = res;
            else if (ck == 1) *(short4v*)(a2r + idx) = res;
            else if (ck == 2) *(short4v*)(p1 + idx) = res;
            else              *(short4v*)(p2 + idx) = res;
          }
        }
      }
    } else {
#pragma unroll
      for (int mf = 0; mf < 2; ++mf) {
        int r = tm * 128 + wr * 32 + mf * 16 + (lane & 15);
        if (r < rows) {
          size_t idx = (size_t)r * 256 + colq;
          short4v p1v = *(const short4v*)(p1 + idx);
          short4v p2v = *(const short4v*)(p2 + idx);
          short4v zbv = *(const short4v*)(zb + idx);
          int gr = row_off + r;
          int node = lvl_start + (gr >> 6);
          int b = gr & 63;
          short4v hv;
#pragma unroll
          for (int j = 0; j < 4; ++j) {
            float cell = tanhf_(acc[mf][nf][j] + bsv[j]);
            float hid = bf2f((unsigned short)p1v[j]) + bf2f((unsigned short)p2v[j]) +
                        bf2f((unsigned short)zbv[j]) * cell;
            hv[j] = (short)f2bf(hid);
          }
          *(short4v*)(hb + (size_t)node * 16384 + b * 256 + colq) = hv;
        }
      }
    }
  }
}

__global__ __launch_bounds__(512, 4) void k_gates(
    const unsigned short* __restrict__ A0, const unsigned short* __restrict__ A1,
    const unsigned short* __restrict__ A2, const unsigned short* __restrict__ Wt,
    const float* __restrict__ bias, int rows, int row_off, int lvl_start, int nwg,
    const unsigned short* __restrict__ lh, const unsigned short* __restrict__ rh,
    unsigned short* __restrict__ a2l, unsigned short* __restrict__ a2r,
    unsigned short* __restrict__ p1, unsigned short* __restrict__ p2,
    unsigned short* __restrict__ zb) {
  gemm_stg<0>(A0, A1, A2, Wt, bias, rows, row_off, lvl_start, 10, nwg,
              lh, rh, a2l, a2r, p1, p2, zb, nullptr);
}

__global__ __launch_bounds__(512, 4) void k_cell(
    const unsigned short* __restrict__ A0, const unsigned short* __restrict__ A1,
    const unsigned short* __restrict__ A2, const unsigned short* __restrict__ Wt,
    const float* __restrict__ bias, int rows, int row_off, int lvl_start, int nwg,
    const unsigned short* __restrict__ p1, const unsigned short* __restrict__ p2,
    const unsigned short* __restrict__ zb, unsigned short* __restrict__ hb) {
  gemm_stg<1>(A0, A1, A2, Wt, bias, rows, row_off, lvl_start, 2, nwg,
              nullptr, nullptr, nullptr, nullptr, (unsigned short*)p1,
              (unsigned short*)p2, (unsigned short*)zb, hb);
}

// ---- leaf kernel: r10 body (reg-staged PF3 dbuf, padded LDS, fp32 A) ----
__global__ __launch_bounds__(512, 4) void k_leaf(
    const float* __restrict__ Af, const unsigned short* __restrict__ Wt,
    const float* __restrict__ bias, const float* __restrict__ bias2, int nwg,
    unsigned short* __restrict__ hb) {
  constexpr int NKT = 4;    // K-steps of 64 (K=256)
  constexpr int LR = 72;
  int t = swz_t(blockIdx.x, nwg);
  int tm = t / 4, tn = t % 4;
  const int tid = threadIdx.x, lane = tid & 63, wave = tid >> 6;
  const int wr = wave >> 1, wcl = wave & 1;

  __shared__ unsigned short As[2][128 * LR];
  __shared__ unsigned short Bs[2][128 * LR];

  f32x4 acc[2][4];
#pragma unroll
  for (int i = 0; i < 2; ++i)
#pragma unroll
    for (int j = 0; j < 4; ++j) {
      f32x4 zv = {0.f, 0.f, 0.f, 0.f};
      acc[i][j] = zv;
    }

  const int srow = tid >> 3;
  const int scol = (tid & 7) * 8;

  short8 rvb[3][2];
  f32x4 fva[3][2][2];

  auto LOADK = [&](int kt, int s) {
    int ko = (kt & 3) * 64;
#pragma unroll
    for (int i = 0; i < 2; ++i) {
      int row = srow + i * 64;
      const float* ap = Af + (size_t)(tm * 128 + row) * 256 + ko + scol;
      fva[s][i][0] = *(const f32x4*)(ap);
      fva[s][i][1] = *(const f32x4*)(ap + 4);
      rvb[s][i] = *(const short8*)(Wt + (size_t)(tn * 128 + row) * 256 + kt * 64 + scol);
    }
  };
  auto WRITEK = [&](int s, int buf) {
#pragma unroll
    for (int i = 0; i < 2; ++i) {
      int row = srow + i * 64;
      short8 v;
#pragma unroll
      for (int j = 0; j < 4; ++j) {
        v[j] = (short)f2bf(fva[s][i][0][j]);
        v[j + 4] = (short)f2bf(fva[s][i][1][j]);
      }
      *(short8*)(&As[buf][row * LR + scol]) = v;
      *(short8*)(&Bs[buf][row * LR + scol]) = rvb[s][i];
    }
  };

  LOADK(0, 0);
  LOADK(1, 1);
  LOADK(2, 2);
  WRITEK(0, 0);
  bar_lgkm();

#pragma unroll
  for (int kt = 0; kt < NKT; ++kt) {
    const int cur = kt & 1;
    if (kt + 1 < NKT) WRITEK((kt + 1) % 3, cur ^ 1);
    if (kt + 3 < NKT) LOADK(kt + 3, kt % 3);
#pragma unroll
    for (int kk = 0; kk < 2; ++kk) {
      short8 af[2], bf[4];
#pragma unroll
      for (int mf = 0; mf < 2; ++mf)
        af[mf] = *(const short8*)(&As[cur][(wr * 32 + mf * 16 + (lane & 15)) * LR + kk * 32 + (lane >> 4) * 8]);
#pragma unroll
      for (int nf = 0; nf < 4; ++nf)
        bf[nf] = *(const short8*)(&Bs[cur][(wcl * 64 + nf * 16 + (lane & 15)) * LR + kk * 32 + (lane >> 4) * 8]);
#pragma unroll
      for (int mf = 0; mf < 2; ++mf)
#pragma unroll
        for (int nf = 0; nf < 4; ++nf)
          acc[mf][nf] = __builtin_amdgcn_mfma_f32_16x16x32_bf16(bf[nf], af[mf], acc[mf][nf], 0, 0, 0);
    }
    if (kt + 1 < NKT) bar_lgkm();
  }

  // leaf epilogue: even 16-col groups = z, odd = c (interleaved Wl)
#pragma unroll
  for (int nfp = 0; nfp < 2; ++nfp) {
    int nz = nfp * 2;
    int g = tn * 8 + wcl * 4 + nz;                 // even group id
    int hcq = (g >> 1) * 16 + (lane >> 4) * 4;     // quad base in h-col space
    f32x4 bzv = *(const f32x4*)(bias + 1024 + hcq);
    f32x4 bcv = *(const f32x4*)(bias2 + hcq);
#pragma unroll
    for (int mf = 0; mf < 2; ++mf) {
      int r = tm * 128 + wr * 32 + mf * 16 + (lane & 15);
      int node = 256 + (r >> 6), b = r & 63;
      short4v hv;
#pragma unroll
      for (int j = 0; j < 4; ++j) {
        float h = sigmf(acc[mf][nz][j] + bzv[j]) * tanhf_(acc[mf][nz + 1][j] + bcv[j]);
        hv[j] = (short)f2bf(h);
      }
      *(short4v*)(hb + (size_t)node * 16384 + b * 256 + hcq) = hv;
    }
  }
}

// ---- final output from hb: coalesced fp32 writes ----
// out[b,i,k] = h[(i+1)%1024][b][k]; out2[b,k] = h[0][b][k]
__global__ __launch_bounds__(256) void k_write_out(const unsigned short* __restrict__ hb,
                                                   float* __restrict__ out) {
  long long t = (long long)blockIdx.x * 256 + threadIdx.x;
  long long e = t * 8;
  const long long main_n = 16777216LL;  // 64*1024*256
  if (e < main_n) {
    int b = (int)(e >> 18);
    int rem = (int)(e & 262143);
    int i = rem >> 8;
    int k = rem & 255;
    int node = (i + 1) & 1023;
    short8 v = *(const short8*)(hb + (size_t)node * 16384 + b * 256 + k);
    float4 o0, o1;
    o0.x = bf2f((unsigned short)v[0]); o0.y = bf2f((unsigned short)v[1]);
    o0.z = bf2f((unsigned short)v[2]); o0.w = bf2f((unsigned short)v[3]);
    o1.x = bf2f((unsigned short)v[4]); o1.y = bf2f((unsigned short)v[5]);
    o1.z = bf2f((unsigned short)v[6]); o1.w = bf2f((unsigned short)v[7]);
    *(float4*)(out + e) = o0;
    *(float4*)(out + e + 4) = o1;
  } else if (e < main_n + 16384) {
    int e2 = (int)(e - main_n);
    int b = e2 >> 8, k = e2 & 255;
    short8 v = *(const short8*)(hb + (size_t)b * 256 + k);  // node 0
    float4 o0, o1;
    o0.x = bf2f((unsigned short)v[0]); o0.y = bf2f((unsigned short)v[1]);
    o0.z = bf2f((unsigned short)v[2]); o0.w = bf2f((unsigned short)v[3]);
    o1.x = bf2f((unsigned short)v[4]); o1.y = bf2f((unsigned short)v[5]);
    o1.z = bf2f((unsigned short)v[6]); o1.w = bf2f((unsigned short)v[7]);
    *(float4*)(out + e) = o0;
    *(float4*)(out + e + 4) = o1;
  }
}

extern "C" void kernel_launch(void* const* d_in, const int* in_sizes, int n_in,
                              void* d_out, int out_size, void* d_ws, size_t ws_size,
                              hipStream_t stream) {
  const float* inputs = (const float*)d_in[0];
  const float* W_gih = (const float*)d_in[3];
  const float* b_gih = (const float*)d_in[4];
  const float* W_glh = (const float*)d_in[5];
  const float* W_grh = (const float*)d_in[6];
  const float* W_cih = (const float*)d_in[7];
  const float* b_cih = (const float*)d_in[8];
  const float* W_clh = (const float*)d_in[9];
  const float* W_crh = (const float*)d_in[10];
  float* out = (float*)d_out;

  char* ws = (char*)d_ws;
  size_t cur = 0;
  auto alloc = [&](size_t bytes) -> char* {
    char* p = ws + cur;
    cur += (bytes + 255) & ~(size_t)255;
    return p;
  };

  // xb holds only internal x rows (0..16383) + pad for tail-block overreads
  unsigned short* xb = (unsigned short*)alloc((size_t)(16384 + 128) * 256 * 2);
  unsigned short* hb = (unsigned short*)alloc((size_t)1025 * 16384 * 2);
  unsigned short* Wg = (unsigned short*)alloc((size_t)1280 * 768 * 2);
  unsigned short* Wc = (unsigned short*)alloc((size_t)256 * 768 * 2);
  unsigned short* Wl = (unsigned short*)alloc((size_t)512 * 256 * 2);

  size_t rem = (ws_size > cur) ? (ws_size - cur) : 0;
  long long rcap = (long long)(rem / (7 * 512 + 64));
  rcap = (rcap / 128) * 128;
  int Rchunk = (int)((rcap < 11008) ? rcap : 11008);  // max internal level = 10944 rows
  if (Rchunk < 128) Rchunk = 128;

  unsigned short* lh  = (unsigned short*)alloc((size_t)Rchunk * 512);
  unsigned short* rh  = (unsigned short*)alloc((size_t)Rchunk * 512);
  unsigned short* a2l = (unsigned short*)alloc((size_t)Rchunk * 512);
  unsigned short* a2r = (unsigned short*)alloc((size_t)Rchunk * 512);
  unsigned short* p1  = (unsigned short*)alloc((size_t)Rchunk * 512);
  unsigned short* p2  = (unsigned short*)alloc((size_t)Rchunk * 512);
  unsigned short* zb  = (unsigned short*)alloc((size_t)Rchunk * 512);

  k_pre<<<5120, 256, 0, stream>>>(inputs, W_gih, W_glh, W_grh, W_cih, W_clh, W_crh,
                                  xb, Wg, Wc, Wl, hb);

  // leaves (nodes 256..1023): 49152 rows, N=512 interleaved, K=256, fp32-direct A
  k_leaf<<<1536, 512, 0, stream>>>(inputs + (size_t)16384 * 256, Wl, b_gih, b_cih, 1536, hb);

  // internal levels bottom-up
  static const int LSi[5] = {0, 1, 5, 21, 85};
  static const int LCi[5] = {1, 4, 16, 64, 171};

  for (int d = 4; d >= 0; --d) {
    int rows_lvl = LCi[d] * 64;
    for (int off = 0; off < rows_lvl; off += Rchunk) {
      int rows = rows_lvl - off;
      if (rows > Rchunk) rows = Rchunk;
      int tmn = (rows + 127) / 128;
      int pgrid = (rows * 32 + 255) / 256;
      k_prep<<<pgrid, 256, 0, stream>>>(hb, lh, rh, rows, off, LSi[d]);
      const unsigned short* xseg = xb + (size_t)(LSi[d] * 64 + off) * 256;
      int nwg_g = tmn * 10;
      k_gates<<<nwg_g, 512, 0, stream>>>(xseg, lh, rh, Wg, b_gih, rows, off, LSi[d], nwg_g,
                                         lh, rh, a2l, a2r, p1, p2, zb);
      int nwg_c = tmn * 2;
      k_cell<<<nwg_c, 512, 0, stream>>>(xseg, a2l, a2r, Wc, b_cih, rows, off, LSi[d], nwg_c,
                                        p1, p2, zb, hb);
    }
  }

  k_write_out<<<8200, 256, 0, stream>>>(hb, out);
}

// Round 14
// 255.728 us; speedup vs baseline: 1.2475x; 1.0929x over previous
//
#include <hip/hip_runtime.h>

// DTTreeGRU: L=1024, B=64, D=256, H=256, K=4 (tree arity)
// Heap tree: internal nodes 0..255, leaves 256..1023 (children 4n+1..4n+4).
// Internal levels (bottom-up): starts {0,1,5,21,85}, counts {1,4,16,64,171}.
// Leaves: lh=rh=0 -> h = sigmoid(x@Wz^T+bz) * tanh(x@Wc^T+bc): one GEMM over
// interleaved Wl (512 x 256; 16-col z/c groups so z,c pair within one wave).
//
// r14 = r10 (measured best: BK=64, LR=72 padded dbuf LDS, reg-staged PF3,
// lgkm-only barriers, swapped-operand MFMA -> C^T vector epilogues) +
// direct fp32-out writes from cell/leaf epilogues (C^T map gives 64B-sector
// groups, no amplification; validated in r11) and k_write_out dropped.
// r13 lesson: zero bank conflicts != faster — conflicts were a non-factor
// after r4's padding; the 128^2 K-loop is at its structural ceiling.

#define L_TOT 1024

typedef __attribute__((ext_vector_type(8))) short short8;
typedef __attribute__((ext_vector_type(4))) short short4v;
typedef __attribute__((ext_vector_type(4))) float f32x4;

static __device__ __forceinline__ float bf2f(unsigned short u) {
  unsigned int x = ((unsigned int)u) << 16;
  return __builtin_bit_cast(float, x);
}
static __device__ __forceinline__ unsigned short f2bf(float f) {
  unsigned int u = __builtin_bit_cast(unsigned int, f);
  u += 0x7fffu + ((u >> 16) & 1u);
  return (unsigned short)(u >> 16);
}
static __device__ __forceinline__ float sigmf(float x) { return 1.0f / (1.0f + __expf(-x)); }
static __device__ __forceinline__ float tanhf_(float x) { return 2.0f / (1.0f + __expf(-2.0f * x)) - 1.0f; }

// lgkm-only barrier: LDS ops visible, global loads stay in flight
static __device__ __forceinline__ void bar_lgkm() {
  asm volatile("s_waitcnt lgkmcnt(0)" ::: "memory");
  __builtin_amdgcn_s_barrier();
  __builtin_amdgcn_sched_barrier(0);
}

// bijective XCD swizzle (m204): contiguous logical range per XCD
static __device__ __forceinline__ int swz_t(int orig, int nwg) {
  int q = nwg >> 3, r = nwg & 7, x = orig & 7, s = orig >> 3;
  return (x < r ? x * (q + 1) : r * (q + 1) + (x - r) * q) + s;
}

// ---- prologue: convert INTERNAL x rows -> bf16, build weights, zero pad ----
__global__ __launch_bounds__(256) void k_pre(
    const float* __restrict__ in,
    const float* __restrict__ Wgih, const float* __restrict__ Wglh, const float* __restrict__ Wgrh,
    const float* __restrict__ Wcih, const float* __restrict__ Wclh, const float* __restrict__ Wcrh,
    unsigned short* __restrict__ xb, unsigned short* __restrict__ Wg,
    unsigned short* __restrict__ Wc, unsigned short* __restrict__ Wl,
    unsigned short* __restrict__ hb) {
  int t = blockIdx.x * 256 + threadIdx.x;
  if (t < 524288) {
    const float* s = in + (size_t)t * 8;
    short8 v;
#pragma unroll
    for (int j = 0; j < 8; ++j) v[j] = (short)f2bf(s[j]);
    *(short8*)(xb + (size_t)t * 8) = v;
  }
  const int NG = 1280 * 768;
  const int NC = 256 * 768;
  const int NL = 512 * 256;
  if (t < NG) {
    int g = t / 768, k = t % 768;
    float v = (k < 256) ? Wgih[g * 256 + k] : ((k < 512) ? Wglh[g * 256 + k - 256] : Wgrh[g * 256 + k - 512]);
    Wg[t] = f2bf(v);
  } else if (t < NG + NC) {
    int t2 = t - NG;
    int g = t2 / 768, k = t2 % 768;
    float v = (k < 256) ? Wcih[g * 256 + k] : ((k < 512) ? Wclh[g * 256 + k - 256] : Wcrh[g * 256 + k - 512]);
    Wc[t2] = f2bf(v);
  } else if (t < NG + NC + NL) {
    int t2 = t - NG - NC;
    int n = t2 >> 8, k = t2 & 255;
    int g = n >> 4;
    int hc = (g >> 1) * 16 + (n & 15);
    float v = (g & 1) ? Wcih[hc * 256 + k] : Wgih[(1024 + hc) * 256 + k];
    Wl[t2] = f2bf(v);
  }
  if (t < 16384) hb[(size_t)1024 * 16384 + t] = 0;  // zero slot (node 255's 4th child)
}

// ---- per-level: lh = h[c0]+h[c1], rh = h[c2]+h[c3]; 8 elems/thread ----
__global__ __launch_bounds__(256) void k_prep(const unsigned short* __restrict__ hb,
                                              unsigned short* __restrict__ lh,
                                              unsigned short* __restrict__ rh,
                                              int rows, int row_off, int lvl_start) {
  int t = blockIdx.x * 256 + threadIdx.x;
  if (t >= rows * 32) return;
  int r = t >> 5, k8 = (t & 31) << 3;
  int gr = row_off + r;
  int node = lvl_start + (gr >> 6);
  int b = gr & 63;
  int cb = 4 * node + 1;
  int c0 = cb, c1 = cb + 1, c2 = cb + 2, c3 = cb + 3;
  c0 = (c0 < L_TOT) ? c0 : L_TOT;
  c1 = (c1 < L_TOT) ? c1 : L_TOT;
  c2 = (c2 < L_TOT) ? c2 : L_TOT;
  c3 = (c3 < L_TOT) ? c3 : L_TOT;
  const short8 v0 = *(const short8*)(hb + (size_t)c0 * 16384 + b * 256 + k8);
  const short8 v1 = *(const short8*)(hb + (size_t)c1 * 16384 + b * 256 + k8);
  const short8 v2 = *(const short8*)(hb + (size_t)c2 * 16384 + b * 256 + k8);
  const short8 v3 = *(const short8*)(hb + (size_t)c3 * 16384 + b * 256 + k8);
  short8 ol, orr;
#pragma unroll
  for (int j = 0; j < 8; ++j) {
    ol[j] = (short)f2bf(bf2f((unsigned short)v0[j]) + bf2f((unsigned short)v1[j]));
    orr[j] = (short)f2bf(bf2f((unsigned short)v2[j]) + bf2f((unsigned short)v3[j]));
  }
  *(short8*)(lh + (size_t)r * 256 + k8) = ol;
  *(short8*)(rh + (size_t)r * 256 + k8) = orr;
}

// ---- reg-staged PF3 dbuf MFMA GEMM, 128x128 tile, 8 waves, LR=72 ----
// Swapped-operand MFMA: acc holds C^T fragments (m = lane&15, n = quad).
// EPI 0: gates (N=1280, K=768): sigmoid + vector scatter a2l/a2r/p1/p2/zb
// EPI 1: cell  (N=256,  K=768): tanh + hidden -> hb (bf16) + out (fp32)
// EPI 2: leaf  (N=512 interleaved Wl, K=256): fp32-direct A; sig*tanh -> hb+out
template <int EPI>
static __device__ __forceinline__ void gemm_body(
    const float* __restrict__ Af,
    const unsigned short* __restrict__ Aseg0,
    const unsigned short* __restrict__ Aseg1,
    const unsigned short* __restrict__ Aseg2,
    const unsigned short* __restrict__ Wt, const float* __restrict__ bias,
    const float* __restrict__ bias2,
    int rows, int row_off, int lvl_start, int NT, int nwg,
    const unsigned short* __restrict__ lh, const unsigned short* __restrict__ rh,
    unsigned short* __restrict__ a2l, unsigned short* __restrict__ a2r,
    unsigned short* __restrict__ p1, unsigned short* __restrict__ p2,
    unsigned short* __restrict__ zb, unsigned short* __restrict__ hb,
    float* __restrict__ out) {
  constexpr int NKT = (EPI == 2) ? 4 : 12;         // K-steps of 64
  constexpr int WSTRIDE = (EPI == 2) ? 256 : 768;  // B row stride
  constexpr int LR = 72;                           // padded LDS row; 144 B = 9*16B
  int t = swz_t(blockIdx.x, nwg);
  int tm = t / NT, tn = t % NT;
  const int tid = threadIdx.x, lane = tid & 63, wave = tid >> 6;
  const int wr = wave >> 1, wcl = wave & 1;  // 4x2 wave grid; wave owns 32x64

  __shared__ unsigned short As[2][128 * LR];
  __shared__ unsigned short Bs[2][128 * LR];

  f32x4 acc[2][4];
#pragma unroll
  for (int i = 0; i < 2; ++i)
#pragma unroll
    for (int j = 0; j < 4; ++j) {
      f32x4 zv = {0.f, 0.f, 0.f, 0.f};
      acc[i][j] = zv;
    }

  const unsigned short* segs[3] = {Aseg0, Aseg1, Aseg2};
  const int srow = tid >> 3;
  const int scol = (tid & 7) * 8;

  // PF3 staging sets (fully unrolled loop -> static indexing)
  short8 rva[3][2], rvb[3][2];
  f32x4 fva[3][2][2];

  auto LOADK = [&](int kt, int s) {
    int ko = (kt & 3) * 64;
#pragma unroll
    for (int i = 0; i < 2; ++i) {
      int row = srow + i * 64;
      if (EPI == 2) {
        const float* ap = Af + (size_t)(tm * 128 + row) * 256 + ko + scol;
        fva[s][i][0] = *(const f32x4*)(ap);
        fva[s][i][1] = *(const f32x4*)(ap + 4);
      } else {
        const unsigned short* segp = segs[kt >> 2];
        rva[s][i] = *(const short8*)(segp + (size_t)(tm * 128 + row) * 256 + ko + scol);
      }
      rvb[s][i] = *(const short8*)(Wt + (size_t)(tn * 128 + row) * WSTRIDE + kt * 64 + scol);
    }
  };
  auto WRITEK = [&](int s, int buf) {
#pragma unroll
    for (int i = 0; i < 2; ++i) {
      int row = srow + i * 64;
      short8 v;
      if (EPI == 2) {
#pragma unroll
        for (int j = 0; j < 4; ++j) {
          v[j] = (short)f2bf(fva[s][i][0][j]);
          v[j + 4] = (short)f2bf(fva[s][i][1][j]);
        }
      } else {
        v = rva[s][i];
      }
      *(short8*)(&As[buf][row * LR + scol]) = v;
      *(short8*)(&Bs[buf][row * LR + scol]) = rvb[s][i];
    }
  };

  // prologue: 3 tiles in flight; tile 0 into LDS buf0
  LOADK(0, 0);
  LOADK(1, 1);
  if (NKT > 2) LOADK(2, 2);
  WRITEK(0, 0);
  bar_lgkm();

#pragma unroll
  for (int kt = 0; kt < NKT; ++kt) {
    const int cur = kt & 1;
    if (kt + 1 < NKT) WRITEK((kt + 1) % 3, cur ^ 1);  // counted vmcnt (tile kt+1)
    if (kt + 3 < NKT) LOADK(kt + 3, kt % 3);          // refill freed set
#pragma unroll
    for (int kk = 0; kk < 2; ++kk) {
      short8 af[2], bf[4];
#pragma unroll
      for (int mf = 0; mf < 2; ++mf)
        af[mf] = *(const short8*)(&As[cur][(wr * 32 + mf * 16 + (lane & 15)) * LR + kk * 32 + (lane >> 4) * 8]);
#pragma unroll
      for (int nf = 0; nf < 4; ++nf)
        bf[nf] = *(const short8*)(&Bs[cur][(wcl * 64 + nf * 16 + (lane & 15)) * LR + kk * 32 + (lane >> 4) * 8]);
      // swapped operands: acc = W-frag x A-frag = C^T fragment
#pragma unroll
      for (int mf = 0; mf < 2; ++mf)
#pragma unroll
        for (int nf = 0; nf < 4; ++nf)
          acc[mf][nf] = __builtin_amdgcn_mfma_f32_16x16x32_bf16(bf[nf], af[mf], acc[mf][nf], 0, 0, 0);
    }
    if (kt + 1 < NKT) bar_lgkm();
  }

  // ---- epilogue: C^T lane map: m-row = ..+(lane&15), n-col quad = ..+(lane>>4)*4+j ----
  if (EPI == 2) {
#pragma unroll
    for (int nfp = 0; nfp < 2; ++nfp) {
      int nz = nfp * 2;
      int g = tn * 8 + wcl * 4 + nz;                 // even group id
      int hcq = (g >> 1) * 16 + (lane >> 4) * 4;     // quad base in h-col space
      f32x4 bzv = *(const f32x4*)(bias + 1024 + hcq);
      f32x4 bcv = *(const f32x4*)(bias2 + hcq);
#pragma unroll
      for (int mf = 0; mf < 2; ++mf) {
        int r = tm * 128 + wr * 32 + mf * 16 + (lane & 15);
        int node = 256 + (r >> 6), b = r & 63;
        short4v hv;
        float4 ov;
#pragma unroll
        for (int j = 0; j < 4; ++j) {
          float h = sigmf(acc[mf][nz][j] + bzv[j]) * tanhf_(acc[mf][nz + 1][j] + bcv[j]);
          hv[j] = (short)f2bf(h);
          ((float*)&ov)[j] = h;
        }
        *(short4v*)(hb + (size_t)node * 16384 + b * 256 + hcq) = hv;
        *(float4*)(out + (size_t)b * 262144 + (size_t)(node - 1) * 256 + hcq) = ov;
      }
    }
    return;
  }
#pragma unroll
  for (int nf = 0; nf < 4; ++nf) {
    int colq = tn * 128 + wcl * 64 + nf * 16 + (lane >> 4) * 4;
    f32x4 bsv = *(const f32x4*)(bias + colq);
    if (EPI == 0) {
      int ck = colq >> 8;        // uniform per block
      int gcq = colq & 255;
#pragma unroll
      for (int mf = 0; mf < 2; ++mf) {
        int r = tm * 128 + wr * 32 + mf * 16 + (lane & 15);
        if (r < rows) {
          size_t idx = (size_t)r * 256 + gcq;
          f32x4 s;
#pragma unroll
          for (int j = 0; j < 4; ++j) s[j] = sigmf(acc[mf][nf][j] + bsv[j]);
          short4v res;
          if (ck == 4) {
#pragma unroll
            for (int j = 0; j < 4; ++j) res[j] = (short)f2bf(s[j]);
            *(short4v*)(zb + idx) = res;
          } else {
            const unsigned short* src = (ck == 0 || ck == 2) ? lh : rh;
            short4v hv = *(const short4v*)(src + idx);
#pragma unroll
            for (int j = 0; j < 4; ++j) res[j] = (short)f2bf(s[j] * bf2f((unsigned short)hv[j]));
            if (ck == 0)      *(short4v*)(a2l + idx) = res;
            else if (ck == 1) *(short4v*)(a2r + idx) = res;
            else if (ck == 2) *(short4v*)(p1 + idx) = res;
            else              *(short4v*)(p2 + idx) = res;
          }
        }
      }
    } else {
#pragma unroll
      for (int mf = 0; mf < 2; ++mf) {
        int r = tm * 128 + wr * 32 + mf * 16 + (lane & 15);
        if (r < rows) {
          size_t idx = (size_t)r * 256 + colq;
          short4v p1v = *(const short4v*)(p1 + idx);
          short4v p2v = *(const short4v*)(p2 + idx);
          short4v zbv = *(const short4v*)(zb + idx);
          int gr = row_off + r;
          int node = lvl_start + (gr >> 6);
          int b = gr & 63;
          short4v hv;
          float4 ov;
#pragma unroll
          for (int j = 0; j < 4; ++j) {
            float cell = tanhf_(acc[mf][nf][j] + bsv[j]);
            float hid = bf2f((unsigned short)p1v[j]) + bf2f((unsigned short)p2v[j]) +
                        bf2f((unsigned short)zbv[j]) * cell;
            hv[j] = (short)f2bf(hid);
            ((float*)&ov)[j] = hid;
          }
          *(short4v*)(hb + (size_t)node * 16384 + b * 256 + colq) = hv;
          int jj = node ? (node - 1) : 1023;
          *(float4*)(out + (size_t)b * 262144 + (size_t)jj * 256 + colq) = ov;
          if (node == 0)
            *(float4*)(out + 16777216 + (size_t)b * 256 + colq) = ov;
        }
      }
    }
  }
}

__global__ __launch_bounds__(512, 4) void k_gates(
    const unsigned short* __restrict__ A0, const unsigned short* __restrict__ A1,
    const unsigned short* __restrict__ A2, const unsigned short* __restrict__ Wt,
    const float* __restrict__ bias, int rows, int row_off, int lvl_start, int nwg,
    const unsigned short* __restrict__ lh, const unsigned short* __restrict__ rh,
    unsigned short* __restrict__ a2l, unsigned short* __restrict__ a2r,
    unsigned short* __restrict__ p1, unsigned short* __restrict__ p2,
    unsigned short* __restrict__ zb) {
  gemm_body<0>(nullptr, A0, A1, A2, Wt, bias, nullptr, rows, row_off, lvl_start, 10, nwg,
               lh, rh, a2l, a2r, p1, p2, zb, nullptr, nullptr);
}

__global__ __launch_bounds__(512, 4) void k_cell(
    const unsigned short* __restrict__ A0, const unsigned short* __restrict__ A1,
    const unsigned short* __restrict__ A2, const unsigned short* __restrict__ Wt,
    const float* __restrict__ bias, int rows, int row_off, int lvl_start, int nwg,
    const unsigned short* __restrict__ p1, const unsigned short* __restrict__ p2,
    const unsigned short* __restrict__ zb, unsigned short* __restrict__ hb,
    float* __restrict__ out) {
  gemm_body<1>(nullptr, A0, A1, A2, Wt, bias, nullptr, rows, row_off, lvl_start, 2, nwg,
               nullptr, nullptr, nullptr, nullptr, (unsigned short*)p1,
               (unsigned short*)p2, (unsigned short*)zb, hb, out);
}

__global__ __launch_bounds__(512, 4) void k_leaf(
    const float* __restrict__ X, const unsigned short* __restrict__ Wl,
    const float* __restrict__ bg, const float* __restrict__ bc, int nwg,
    unsigned short* __restrict__ hb, float* __restrict__ out) {
  gemm_body<2>(X, nullptr, nullptr, nullptr, Wl, bg, bc, 49152, 0, 0, 4, nwg,
               nullptr, nullptr, nullptr, nullptr, nullptr, nullptr, nullptr, hb, out);
}

extern "C" void kernel_launch(void* const* d_in, const int* in_sizes, int n_in,
                              void* d_out, int out_size, void* d_ws, size_t ws_size,
                              hipStream_t stream) {
  const float* inputs = (const float*)d_in[0];
  const float* W_gih = (const float*)d_in[3];
  const float* b_gih = (const float*)d_in[4];
  const float* W_glh = (const float*)d_in[5];
  const float* W_grh = (const float*)d_in[6];
  const float* W_cih = (const float*)d_in[7];
  const float* b_cih = (const float*)d_in[8];
  const float* W_clh = (const float*)d_in[9];
  const float* W_crh = (const float*)d_in[10];
  float* out = (float*)d_out;

  char* ws = (char*)d_ws;
  size_t cur = 0;
  auto alloc = [&](size_t bytes) -> char* {
    char* p = ws + cur;
    cur += (bytes + 255) & ~(size_t)255;
    return p;
  };

  // xb holds only internal x rows (0..16383) + pad for tail-block overreads
  unsigned short* xb = (unsigned short*)alloc((size_t)(16384 + 128) * 256 * 2);
  unsigned short* hb = (unsigned short*)alloc((size_t)1025 * 16384 * 2);
  unsigned short* Wg = (unsigned short*)alloc((size_t)1280 * 768 * 2);
  unsigned short* Wc = (unsigned short*)alloc((size_t)256 * 768 * 2);
  unsigned short* Wl = (unsigned short*)alloc((size_t)512 * 256 * 2);

  size_t rem = (ws_size > cur) ? (ws_size - cur) : 0;
  long long rcap = (long long)(rem / (7 * 512 + 64));
  rcap = (rcap / 128) * 128;
  int Rchunk = (int)((rcap < 11008) ? rcap : 11008);  // max internal level = 10944 rows
  if (Rchunk < 128) Rchunk = 128;

  unsigned short* lh  = (unsigned short*)alloc((size_t)Rchunk * 512);
  unsigned short* rh  = (unsigned short*)alloc((size_t)Rchunk * 512);
  unsigned short* a2l = (unsigned short*)alloc((size_t)Rchunk * 512);
  unsigned short* a2r = (unsigned short*)alloc((size_t)Rchunk * 512);
  unsigned short* p1  = (unsigned short*)alloc((size_t)Rchunk * 512);
  unsigned short* p2  = (unsigned short*)alloc((size_t)Rchunk * 512);
  unsigned short* zb  = (unsigned short*)alloc((size_t)Rchunk * 512);

  k_pre<<<5120, 256, 0, stream>>>(inputs, W_gih, W_glh, W_grh, W_cih, W_clh, W_crh,
                                  xb, Wg, Wc, Wl, hb);

  // leaves (nodes 256..1023): 49152 rows, N=512 interleaved, K=256, fp32-direct A
  k_leaf<<<1536, 512, 0, stream>>>(inputs + (size_t)16384 * 256, Wl, b_gih, b_cih, 1536, hb, out);

  // internal levels bottom-up
  static const int LSi[5] = {0, 1, 5, 21, 85};
  static const int LCi[5] = {1, 4, 16, 64, 171};

  for (int d = 4; d >= 0; --d) {
    int rows_lvl = LCi[d] * 64;
    for (int off = 0; off < rows_lvl; off += Rchunk) {
      int rows = rows_lvl - off;
      if (rows > Rchunk) rows = Rchunk;
      int tmn = (rows + 127) / 128;
      int pgrid = (rows * 32 + 255) / 256;
      k_prep<<<pgrid, 256, 0, stream>>>(hb, lh, rh, rows, off, LSi[d]);
      const unsigned short* xseg = xb + (size_t)(LSi[d] * 64 + off) * 256;
      int nwg_g = tmn * 10;
      k_gates<<<nwg_g, 512, 0, stream>>>(xseg, lh, rh, Wg, b_gih, rows, off, LSi[d], nwg_g,
                                         lh, rh, a2l, a2r, p1, p2, zb);
      int nwg_c = tmn * 2;
      k_cell<<<nwg_c, 512, 0, stream>>>(xseg, a2l, a2r, Wc, b_cih, rows, off, LSi[d], nwg_c,
                                        p1, p2, zb, hb, out);
    }
  }
}